// Round 13
// baseline (307.716 us; speedup 1.0000x reference)
//
#include <hip/hip_runtime.h>

#define TAILB 12.0f
#define INV2048 4.8828125e-4f

typedef _Float16 half8 __attribute__((ext_vector_type(8)));
typedef _Float16 half4 __attribute__((ext_vector_type(4)));
typedef __fp16 fp16x2 __attribute__((ext_vector_type(2)));   // pkrtz return type
typedef __attribute__((ext_vector_type(4))) float f32x4;

#define MFMAH __builtin_amdgcn_mfma_f32_16x16x32_f16

// fast softplus: log(1+e^z); abs err ~2^-24 (1+e rounding) — invisible vs margin
__device__ __forceinline__ float softplus_f(float z) {
    return (z > 15.f) ? z : __logf(1.f + __expf(z));
}

// fp16 2-term scaled split (RNE, prep only)
__device__ __forceinline__ void split2h(float v, _Float16& o0, _Float16& o1) {
    _Float16 h0 = (_Float16)v;
    float r1 = v - (float)h0;
    o0 = h0;
    o1 = (_Float16)(r1 * 2048.0f);
}

// pkrtz-based split of 4 values -> two packed half4 planes (RTZ both terms)
__device__ __forceinline__ void split4_pk(const float v[4], half4& p0, half4& p1) {
    fp16x2 lo = __builtin_amdgcn_cvt_pkrtz(v[0], v[1]);
    fp16x2 hi = __builtin_amdgcn_cvt_pkrtz(v[2], v[3]);
    float r0 = (v[0] - (float)lo.x) * 2048.f;
    float r1 = (v[1] - (float)lo.y) * 2048.f;
    float r2 = (v[2] - (float)hi.x) * 2048.f;
    float r3 = (v[3] - (float)hi.y) * 2048.f;
    fp16x2 rlo = __builtin_amdgcn_cvt_pkrtz(r0, r1);
    fp16x2 rhi = __builtin_amdgcn_cvt_pkrtz(r2, r3);
    p0 = (half4){(_Float16)lo.x, (_Float16)lo.y, (_Float16)hi.x, (_Float16)hi.y};
    p1 = (half4){(_Float16)rlo.x, (_Float16)rlo.y, (_Float16)rhi.x, (_Float16)rhi.y};
}

// ---------------- prep: identical layout to v10/v11 ----------------
__global__ __launch_bounds__(256)
void prep_v13(const float* __restrict__ W1, const float* __restrict__ b1,
              const float* __restrict__ W2, const float* __restrict__ W3,
              _Float16* __restrict__ W2F, _Float16* __restrict__ W3F,
              float4* __restrict__ w1p)
{
    int id = blockIdx.x * 256 + threadIdx.x;
    if (id < 65536) {
        int j = id & 7, ln = (id >> 3) & 63, tile = id >> 9;
        int cs = tile & 3, t = (tile >> 2) & 1, wv = (tile >> 3) & 3, l = tile >> 5;
        int n = 32 * wv + 16 * t + (ln & 15);
        int k = 32 * cs + 8 * (ln >> 4) + j;
        _Float16 a, b;
        split2h(W2[l * 16384 + n * 128 + k], a, b);
        W2F[(tile * 2 + 0) * 512 + ln * 8 + j] = a;
        W2F[(tile * 2 + 1) * 512 + ln * 8 + j] = b;
    } else if (id < 90112) {
        int t2 = id - 65536;
        int j = t2 & 7, ln = (t2 >> 3) & 63, tile3 = t2 >> 9;
        int cs = tile3 & 3, q = tile3 >> 2;
        int wv = q % 3, l = q / 3;
        int p = 16 * wv + (ln & 15);
        int n = 32 * cs + 8 * (ln >> 4) + j;
        float v = (p < 46) ? W3[l * 5888 + p * 128 + n] : 0.f;
        _Float16 a, b;
        split2h(v, a, b);
        W3F[(tile3 * 2 + 0) * 512 + ln * 8 + j] = a;
        W3F[(tile3 * 2 + 1) * 512 + ln * 8 + j] = b;
    } else if (id < 90624) {
        int t = id - 90112;
        int l = t >> 7, k = t & 127;
        float4 v;
        v.x = W1[l * 384 + k * 3 + 0];
        v.y = W1[l * 384 + k * 3 + 1];
        v.z = W1[l * 384 + k * 3 + 2];
        v.w = b1[l * 128 + k];
        w1p[t] = v;
    }
}

// v11 structure; changes: launch_bounds (256,4), fast softplus, __fdividef in spline.
__global__ __launch_bounds__(256, 4)
void rqs_v13(const float* __restrict__ inp, const float* __restrict__ cond,
             const _Float16* __restrict__ W2F, const _Float16* __restrict__ W3F,
             const float4* __restrict__ w1p,
             const float* __restrict__ b2, const float* __restrict__ b3,
             float* __restrict__ out, int B)
{
    __shared__ __align__(16) _Float16 planes[2][64][136];   // 34816 B; pbuf overlays
    __shared__ float xbuf[64][5];

    char* plw = (char*)&planes[0][0][0];
    const char* pl = plw;
    float* ladb = (float*)(plw + 13312);       // [128] overlay, used after last barrier

    const int tid  = threadIdx.x;
    const int base = blockIdx.x * 64;
    const int wv   = tid >> 6;
    const int ln   = tid & 63;
    const int sm   = ln & 15;
    const int qd   = ln >> 4;
    const int s1   = tid & 63;                 // phase-1 sample

    // ---- layer-invariant LDS addresses (held in VGPRs) ----
    int rdaddr[4][4];                          // plane reads [st][cs]
    #pragma unroll
    for (int st = 0; st < 4; ++st) {
        int row = 16 * st + sm, key = (row >> 3) & 7;
        #pragma unroll
        for (int cs = 0; cs < 4; ++cs)
            rdaddr[st][cs] = row * 272 + (((4 * cs + qd) ^ key) << 4);
    }
    int wra[8];                                // phase-1 writes [g]
    {
        int key = (s1 >> 3) & 7;
        #pragma unroll
        for (int g = 0; g < 8; ++g)
            wra[g] = s1 * 272 + (((4 * wv + (g >> 1)) ^ key) << 4) + ((g & 1) << 3);
    }
    int ewa[2][4];                             // h2 epilogue writes [t][st]
    #pragma unroll
    for (int t = 0; t < 2; ++t)
        #pragma unroll
        for (int st = 0; st < 4; ++st) {
            int row = 16 * st + sm, key = (row >> 3) & 7;
            int pg = 4 * wv + 2 * t + (qd >> 1);
            ewa[t][st] = row * 272 + ((pg ^ key) << 4) + ((qd & 1) << 3);
        }
    int pwa[4];                                // pbuf b128 writes [st]
    #pragma unroll
    for (int st = 0; st < 4; ++st)
        pwa[st] = (16 * st + sm) * 208 + (16 * wv + 4 * qd) * 4;

    if (tid < 64) {
        float4 xi = reinterpret_cast<const float4*>(inp)[base + tid];
        xbuf[tid][0] = xi.x; xbuf[tid][1] = xi.y;
        xbuf[tid][2] = xi.z; xbuf[tid][3] = xi.w;
        xbuf[tid][4] = cond[base + tid];
    }
    float ladreg = 0.f;
    __syncthreads();

    #pragma unroll 1
    for (int l = 0; l < 4; ++l) {
        int mi0, mi1, ii0, ii1;
        switch (l) {
            case 0:  mi0 = 0; mi1 = 2; ii0 = 1; ii1 = 3; break;
            case 1:  mi0 = 1; mi1 = 3; ii0 = 0; ii1 = 2; break;
            case 2:  mi0 = 0; mi1 = 1; ii0 = 2; ii1 = 3; break;
            default: mi0 = 2; mi1 = 3; ii0 = 0; ii1 = 1; break;
        }

        // ---- phase 1: h1 planes (wave wv covers k in [32wv,+32) for its sample) ----
        {
            float m0 = xbuf[s1][mi0], m1 = xbuf[s1][mi1], cc = xbuf[s1][4];
            const float4* w1l = w1p + l * 128;
            #pragma unroll
            for (int g = 0; g < 8; ++g) {
                int k0 = 32 * wv + 4 * g;
                float v[4];
                #pragma unroll
                for (int r = 0; r < 4; ++r) {
                    float4 w4 = w1l[k0 + r];
                    v[r] = fmaxf(fmaf(w4.x, m0, fmaf(w4.y, m1, fmaf(w4.z, cc, w4.w))), 0.f);
                }
                half4 p0, p1;
                split4_pk(v, p0, p1);
                char* wp = plw + wra[g];
                *(half4*)(wp)          = p0;
                *(half4*)(wp + 17408)  = p1;
            }
        }
        __syncthreads();   // B1: h1 planes ready

        // ---- GEMM2: wave wv -> h2 rows [32wv,+32); bias-in-init; cs unrolled ----
        f32x4 accA[2][4], accB[2][4];
        {
            int nb = __builtin_amdgcn_readfirstlane(l * 128 + 32 * wv);
            #pragma unroll
            for (int t = 0; t < 2; ++t) {
                float4 bias = *(const float4*)(b2 + nb + 16 * t + 4 * qd);
                #pragma unroll
                for (int st = 0; st < 4; ++st) {
                    accA[t][st] = (f32x4){bias.x, bias.y, bias.z, bias.w};
                    accB[t][st] = (f32x4){0.f, 0.f, 0.f, 0.f};
                }
            }
            const half8* W2F8 = (const half8*)W2F;
            int tb = (l * 4 + wv) * 2;
            #pragma unroll
            for (int cs = 0; cs < 4; ++cs) {
                half8 A00 = W2F8[(((tb + 0) * 4 + cs) * 2 + 0) * 64 + ln];
                half8 A01 = W2F8[(((tb + 0) * 4 + cs) * 2 + 1) * 64 + ln];
                half8 A10 = W2F8[(((tb + 1) * 4 + cs) * 2 + 0) * 64 + ln];
                half8 A11 = W2F8[(((tb + 1) * 4 + cs) * 2 + 1) * 64 + ln];
                #pragma unroll
                for (int st = 0; st < 4; ++st) {
                    half8 b0 = *(const half8*)(pl + rdaddr[st][cs]);
                    half8 b1 = *(const half8*)(pl + rdaddr[st][cs] + 17408);
                    accA[0][st] = MFMAH(A00, b0, accA[0][st], 0, 0, 0);
                    accB[0][st] = MFMAH(A00, b1, accB[0][st], 0, 0, 0);
                    accB[0][st] = MFMAH(A01, b0, accB[0][st], 0, 0, 0);
                    accA[1][st] = MFMAH(A10, b0, accA[1][st], 0, 0, 0);
                    accB[1][st] = MFMAH(A10, b1, accB[1][st], 0, 0, 0);
                    accB[1][st] = MFMAH(A11, b0, accB[1][st], 0, 0, 0);
                }
            }
        }
        __syncthreads();   // B2: all h1 reads done -> h2 overwrite safe

        // ---- h2 epilogue: combine, relu, pkrtz split, write planes ----
        {
            #pragma unroll
            for (int t = 0; t < 2; ++t) {
                #pragma unroll
                for (int st = 0; st < 4; ++st) {
                    float v[4];
                    #pragma unroll
                    for (int r = 0; r < 4; ++r)
                        v[r] = fmaxf(fmaf(INV2048, accB[t][st][r], accA[t][st][r]), 0.f);
                    half4 p0, p1;
                    split4_pk(v, p0, p1);
                    char* wp = plw + ewa[t][st];
                    *(half4*)(wp)         = p0;
                    *(half4*)(wp + 17408) = p1;
                }
            }
        }
        __syncthreads();   // B3: h2 planes ready

        // ---- GEMM3: waves 0..2, p-tile 16wv; cs unrolled ----
        f32x4 acc3A[4], acc3B[4];
        #pragma unroll
        for (int st = 0; st < 4; ++st) {
            acc3A[st] = (f32x4){0.f, 0.f, 0.f, 0.f};
            acc3B[st] = (f32x4){0.f, 0.f, 0.f, 0.f};
        }
        if (wv < 3) {
            const half8* W3F8 = (const half8*)W3F;
            int qb = (l * 3 + wv) * 4;
            #pragma unroll
            for (int cs = 0; cs < 4; ++cs) {
                half8 A0 = W3F8[((qb + cs) * 2 + 0) * 64 + ln];
                half8 A1 = W3F8[((qb + cs) * 2 + 1) * 64 + ln];
                #pragma unroll
                for (int st = 0; st < 4; ++st) {
                    half8 b0 = *(const half8*)(pl + rdaddr[st][cs]);
                    half8 b1 = *(const half8*)(pl + rdaddr[st][cs] + 17408);
                    acc3A[st] = MFMAH(A0, b0, acc3A[st], 0, 0, 0);
                    acc3B[st] = MFMAH(A0, b1, acc3B[st], 0, 0, 0);
                    acc3B[st] = MFMAH(A1, b0, acc3B[st], 0, 0, 0);
                }
            }
        }
        __syncthreads();   // B4: all h2 reads done -> pbuf overlay safe

        if (wv < 3) {
            #pragma unroll
            for (int st = 0; st < 4; ++st) {
                float4 pv;
                pv.x = fmaf(INV2048, acc3B[st][0], acc3A[st][0]);
                pv.y = fmaf(INV2048, acc3B[st][1], acc3A[st][1]);
                pv.z = fmaf(INV2048, acc3B[st][2], acc3A[st][2]);
                pv.w = fmaf(INV2048, acc3B[st][3], acc3A[st][3]);
                *(float4*)(plw + pwa[st]) = pv;   // pbuf[row][16wv+4qd .. +3]
            }
        }
        __syncthreads();   // B5: params visible

        // ---- spline: thread (f = tid>>6, s = tid&63); pbuf row-major b128 reads ----
        if (tid < 128) {
            int f = tid >> 6, s = tid & 63;
            const float* b3l = b3 + l * 46;
            const float4* prow = (const float4*)(pl + s * 208);
            float pr[23];
            #pragma unroll
            for (int i = 0; i < 12; ++i) {
                float4 q = prow[i];                     // p = 4i .. 4i+3
                pr[2 * i] = (f ? q.y : q.x) + b3l[4 * i + f];
                if (2 * i + 1 < 23)
                    pr[2 * i + 1] = (f ? q.w : q.z) + b3l[4 * i + 2 + f];
            }

            float xin = xbuf[s][f == 0 ? ii0 : ii1];

            float d[9];
            d[0] = 1.f; d[8] = 1.f;
            #pragma unroll
            for (int k = 1; k < 8; ++k) d[k] = 1e-6f + softplus_f(pr[16 + k - 1]);

            bool inside = (xin >= -TAILB) && (xin <= TAILB);
            float xc = fminf(fmaxf(xin, -TAILB), TAILB);

            float mw = pr[0], mh = pr[8];
            #pragma unroll
            for (int k = 1; k < 8; ++k) { mw = fmaxf(mw, pr[k]); mh = fmaxf(mh, pr[8 + k]); }
            float ew[8], eh[8], swm = 0.f, shm = 0.f;
            #pragma unroll
            for (int k = 0; k < 8; ++k) {
                ew[k] = __expf(pr[k] - mw);     swm += ew[k];
                eh[k] = __expf(pr[8 + k] - mh); shm += eh[k];
            }
            const float c1 = 1.f - 8e-6f;
            float isw = __fdividef(c1, swm), ish = __fdividef(c1, shm);

            float cum_w = 0.f, cum_h = 0.f;
            float cwk = -TAILB, chk = -TAILB;
            float s_cw = -TAILB, s_w = 2.f * TAILB, s_ch = -TAILB, s_h = 2.f * TAILB;
            float s_d0 = 1.f, s_d1 = d[1];
            #pragma unroll
            for (int k = 0; k < 8; ++k) {
                cum_w += fmaf(ew[k], isw, 1e-6f);
                cum_h += fmaf(eh[k], ish, 1e-6f);
                float cwn = (k == 7) ? TAILB : fmaf(2.f * TAILB, cum_w, -TAILB);
                float chn = (k == 7) ? TAILB : fmaf(2.f * TAILB, cum_h, -TAILB);
                bool ge = (xc >= cwk);
                s_cw = ge ? cwk : s_cw;  s_w = ge ? (cwn - cwk) : s_w;
                s_ch = ge ? chk : s_ch;  s_h = ge ? (chn - chk) : s_h;
                s_d0 = ge ? d[k] : s_d0; s_d1 = ge ? d[k + 1] : s_d1;
                cwk = cwn; chk = chn;
            }

            float rw    = __fdividef(1.f, s_w);
            float th    = (xc - s_cw) * rw;
            float delta = s_h * rw;
            float omt   = 1.f - th;
            float tomt  = th * omt;
            float num   = s_h * fmaf(delta, th * th, s_d0 * tomt);
            float den   = fmaf(s_d0 + s_d1 - 2.f * delta, tomt, delta);
            float y     = s_ch + __fdividef(num, den);
            float dnum  = delta * delta * (s_d1 * th * th + 2.f * delta * tomt + s_d0 * omt * omt);
            float lad   = __logf(dnum) - 2.f * __logf(den);

            xbuf[s][f == 0 ? ii0 : ii1] = inside ? y : xin;
            ladreg += inside ? lad : 0.f;
        }
        __syncthreads();   // B6: spline done; next phase1 may overwrite planes
    } // l

    if (tid < 128) ladb[tid] = ladreg;
    __syncthreads();
    if (tid < 64) {
        float4 xo;
        xo.x = xbuf[tid][0]; xo.y = xbuf[tid][1];
        xo.z = xbuf[tid][2]; xo.w = xbuf[tid][3];
        reinterpret_cast<float4*>(out)[base + tid] = xo;
        out[(size_t)B * 4 + base + tid] = ladb[tid] + ladb[tid + 64];
    }
}

extern "C" void kernel_launch(void* const* d_in, const int* in_sizes, int n_in,
                              void* d_out, int out_size, void* d_ws, size_t ws_size,
                              hipStream_t stream) {
    const float* inp  = (const float*)d_in[0];
    const float* cond = (const float*)d_in[1];
    const float* W1   = (const float*)d_in[2];
    const float* b1   = (const float*)d_in[3];
    const float* W2   = (const float*)d_in[4];
    const float* b2   = (const float*)d_in[5];
    const float* W3   = (const float*)d_in[6];
    const float* b3   = (const float*)d_in[7];
    float* out = (float*)d_out;
    int B = in_sizes[0] / 4;

    char* ws = (char*)d_ws;
    _Float16* W2F = (_Float16*)(ws);            // 262144 B
    _Float16* W3F = (_Float16*)(ws + 262144);   // 98304 B
    float4*   w1p = (float4*)(ws + 360448);     // 8192 B

    hipLaunchKernelGGL(prep_v13, dim3(354), dim3(256), 0, stream,
                       W1, b1, W2, W3, W2F, W3F, w1p);
    hipLaunchKernelGGL(rqs_v13, dim3(B / 64), dim3(256), 0, stream,
                       inp, cond, W2F, W3F, w1p, b2, b3, out, B);
}

// Round 14
// 276.292 us; speedup vs baseline: 1.1137x; 1.1137x over previous
//
#include <hip/hip_runtime.h>

#define TAILB 12.0f
#define INV2048 4.8828125e-4f

typedef _Float16 half8 __attribute__((ext_vector_type(8)));
typedef _Float16 half4 __attribute__((ext_vector_type(4)));
typedef __fp16 fp16x2 __attribute__((ext_vector_type(2)));   // pkrtz return type
typedef __attribute__((ext_vector_type(4))) float f32x4;

#define MFMAH __builtin_amdgcn_mfma_f32_16x16x32_f16

// fast softplus: log(1+e^z); abs err ~2^-24 — r13-verified (absmax 0.5)
__device__ __forceinline__ float softplus_f(float z) {
    return (z > 15.f) ? z : __logf(1.f + __expf(z));
}

// fp16 2-term scaled split (RNE, prep only)
__device__ __forceinline__ void split2h(float v, _Float16& o0, _Float16& o1) {
    _Float16 h0 = (_Float16)v;
    float r1 = v - (float)h0;
    o0 = h0;
    o1 = (_Float16)(r1 * 2048.0f);
}

// pkrtz-based split of 4 values -> two packed half4 planes (RTZ both terms)
__device__ __forceinline__ void split4_pk(const float* v, half4& p0, half4& p1) {
    fp16x2 lo = __builtin_amdgcn_cvt_pkrtz(v[0], v[1]);
    fp16x2 hi = __builtin_amdgcn_cvt_pkrtz(v[2], v[3]);
    float r0 = (v[0] - (float)lo.x) * 2048.f;
    float r1 = (v[1] - (float)lo.y) * 2048.f;
    float r2 = (v[2] - (float)hi.x) * 2048.f;
    float r3 = (v[3] - (float)hi.y) * 2048.f;
    fp16x2 rlo = __builtin_amdgcn_cvt_pkrtz(r0, r1);
    fp16x2 rhi = __builtin_amdgcn_cvt_pkrtz(r2, r3);
    p0 = (half4){(_Float16)lo.x, (_Float16)lo.y, (_Float16)hi.x, (_Float16)hi.y};
    p1 = (half4){(_Float16)rlo.x, (_Float16)rlo.y, (_Float16)rhi.x, (_Float16)rhi.y};
}

// ---------------- prep: identical layout to v10/v11/v13 ----------------
__global__ __launch_bounds__(256)
void prep_v14(const float* __restrict__ W1, const float* __restrict__ b1,
              const float* __restrict__ W2, const float* __restrict__ W3,
              _Float16* __restrict__ W2F, _Float16* __restrict__ W3F,
              float4* __restrict__ w1p)
{
    int id = blockIdx.x * 256 + threadIdx.x;
    if (id < 65536) {
        int j = id & 7, ln = (id >> 3) & 63, tile = id >> 9;
        int cs = tile & 3, t = (tile >> 2) & 1, wv = (tile >> 3) & 3, l = tile >> 5;
        int n = 32 * wv + 16 * t + (ln & 15);
        int k = 32 * cs + 8 * (ln >> 4) + j;
        _Float16 a, b;
        split2h(W2[l * 16384 + n * 128 + k], a, b);
        W2F[(tile * 2 + 0) * 512 + ln * 8 + j] = a;
        W2F[(tile * 2 + 1) * 512 + ln * 8 + j] = b;
    } else if (id < 90112) {
        int t2 = id - 65536;
        int j = t2 & 7, ln = (t2 >> 3) & 63, tile3 = t2 >> 9;
        int cs = tile3 & 3, q = tile3 >> 2;
        int wv = q % 3, l = q / 3;
        int p = 16 * wv + (ln & 15);
        int n = 32 * cs + 8 * (ln >> 4) + j;
        float v = (p < 46) ? W3[l * 5888 + p * 128 + n] : 0.f;
        _Float16 a, b;
        split2h(v, a, b);
        W3F[(tile3 * 2 + 0) * 512 + ln * 8 + j] = a;
        W3F[(tile3 * 2 + 1) * 512 + ln * 8 + j] = b;
    } else if (id < 90624) {
        int t = id - 90112;
        int l = t >> 7, k = t & 127;
        float4 v;
        v.x = W1[l * 384 + k * 3 + 0];
        v.y = W1[l * 384 + k * 3 + 1];
        v.z = W1[l * 384 + k * 3 + 2];
        v.w = b1[l * 128 + k];
        w1p[t] = v;
    }
}

// 32 samples/block, 8192 blocks, 4 waves. LDS ~17 KB -> 6 blocks/CU residency
// (vs 4 at 64-sample blocks); barrier drains overlap across blocks.
// Planes: 2 x 32 rows x 256 B, full 16-group xor swizzle (key = row&15 = sm):
// read pattern = exactly 8 accesses/bank = structural minimum -> ~0 conflicts.
// Math identical to v10-v13 (A + B/2048 split-fp16 MFMA, absmax 0.5).
__global__ __launch_bounds__(256, 3)
void rqs_v14(const float* __restrict__ inp, const float* __restrict__ cond,
             const _Float16* __restrict__ W2F, const _Float16* __restrict__ W3F,
             const float4* __restrict__ w1p,
             const float* __restrict__ b2, const float* __restrict__ b3,
             float* __restrict__ out, int B)
{
    __shared__ __align__(16) _Float16 planes[2][32][128];   // 16384 B; pbuf overlays
    __shared__ float xbuf[32][5];

    char* plw = (char*)&planes[0][0][0];
    const char* pl = plw;
    float* ladb = (float*)(plw + 6656);        // [64] overlay after pbuf [32][52]

    const int tid  = threadIdx.x;
    const int base = blockIdx.x * 32;
    const int wv   = tid >> 6;
    const int ln   = tid & 63;
    const int sm   = ln & 15;
    const int qd   = ln >> 4;
    const int s1   = tid & 31;                 // phase-1 sample
    const int kh   = tid >> 5;                 // phase-1 k-16-chunk (0..7)

    // ---- layer-invariant LDS addresses ----
    int rdaddr[2][4];                          // plane reads [st][cs]
    #pragma unroll
    for (int st = 0; st < 2; ++st)
        #pragma unroll
        for (int cs = 0; cs < 4; ++cs)
            rdaddr[st][cs] = (16 * st + sm) * 256 + (((4 * cs + qd) ^ sm) << 4);
    int wra[2];                                // phase-1 writes [gi]
    #pragma unroll
    for (int gi = 0; gi < 2; ++gi)
        wra[gi] = s1 * 256 + (((2 * kh + gi) ^ (s1 & 15)) << 4);
    int ewa[2][2];                             // h2 epilogue writes [t][st]
    #pragma unroll
    for (int t = 0; t < 2; ++t)
        #pragma unroll
        for (int st = 0; st < 2; ++st) {
            int g = 4 * wv + 2 * t + (qd >> 1);
            ewa[t][st] = (16 * st + sm) * 256 + ((g ^ sm) << 4) + ((qd & 1) << 3);
        }
    int pwa[2];                                // pbuf b128 writes [st]
    #pragma unroll
    for (int st = 0; st < 2; ++st)
        pwa[st] = (16 * st + sm) * 208 + (16 * wv + 4 * qd) * 4;

    if (tid < 32) {
        float4 xi = reinterpret_cast<const float4*>(inp)[base + tid];
        xbuf[tid][0] = xi.x; xbuf[tid][1] = xi.y;
        xbuf[tid][2] = xi.z; xbuf[tid][3] = xi.w;
        xbuf[tid][4] = cond[base + tid];
    }
    float ladreg = 0.f;
    __syncthreads();

    #pragma unroll 1
    for (int l = 0; l < 4; ++l) {
        int mi0, mi1, ii0, ii1;
        switch (l) {
            case 0:  mi0 = 0; mi1 = 2; ii0 = 1; ii1 = 3; break;
            case 1:  mi0 = 1; mi1 = 3; ii0 = 0; ii1 = 2; break;
            case 2:  mi0 = 0; mi1 = 1; ii0 = 2; ii1 = 3; break;
            default: mi0 = 2; mi1 = 3; ii0 = 0; ii1 = 1; break;
        }

        // ---- phase 1: h1 planes; thread (s1, kh) covers k in [16kh,16kh+16) ----
        {
            float m0 = xbuf[s1][mi0], m1 = xbuf[s1][mi1], cc = xbuf[s1][4];
            const float4* w1l = w1p + l * 128;
            #pragma unroll
            for (int gi = 0; gi < 2; ++gi) {
                int kb = (2 * kh + gi) * 8;
                float v[8];
                #pragma unroll
                for (int r = 0; r < 8; ++r) {
                    float4 w4 = w1l[kb + r];
                    v[r] = fmaxf(fmaf(w4.x, m0, fmaf(w4.y, m1, fmaf(w4.z, cc, w4.w))), 0.f);
                }
                half4 a0, a1, b0h, b1h;
                split4_pk(v, a0, a1);
                split4_pk(v + 4, b0h, b1h);
                half8 p0 = {a0.x, a0.y, a0.z, a0.w, b0h.x, b0h.y, b0h.z, b0h.w};
                half8 p1 = {a1.x, a1.y, a1.z, a1.w, b1h.x, b1h.y, b1h.z, b1h.w};
                char* wp = plw + wra[gi];
                *(half8*)(wp)        = p0;
                *(half8*)(wp + 8192) = p1;
            }
        }
        __syncthreads();   // B1: h1 planes ready

        // ---- GEMM2: wave wv -> h2 rows [32wv,+32); bias-in-init; cs unrolled ----
        f32x4 accA[2][2], accB[2][2];
        {
            int nb = __builtin_amdgcn_readfirstlane(l * 128 + 32 * wv);
            #pragma unroll
            for (int t = 0; t < 2; ++t) {
                float4 bias = *(const float4*)(b2 + nb + 16 * t + 4 * qd);
                #pragma unroll
                for (int st = 0; st < 2; ++st) {
                    accA[t][st] = (f32x4){bias.x, bias.y, bias.z, bias.w};
                    accB[t][st] = (f32x4){0.f, 0.f, 0.f, 0.f};
                }
            }
            const half8* W2F8 = (const half8*)W2F;
            int tb = (l * 4 + wv) * 2;
            #pragma unroll
            for (int cs = 0; cs < 4; ++cs) {
                half8 A00 = W2F8[(((tb + 0) * 4 + cs) * 2 + 0) * 64 + ln];
                half8 A01 = W2F8[(((tb + 0) * 4 + cs) * 2 + 1) * 64 + ln];
                half8 A10 = W2F8[(((tb + 1) * 4 + cs) * 2 + 0) * 64 + ln];
                half8 A11 = W2F8[(((tb + 1) * 4 + cs) * 2 + 1) * 64 + ln];
                #pragma unroll
                for (int st = 0; st < 2; ++st) {
                    half8 b0 = *(const half8*)(pl + rdaddr[st][cs]);
                    half8 b1 = *(const half8*)(pl + rdaddr[st][cs] + 8192);
                    accA[0][st] = MFMAH(A00, b0, accA[0][st], 0, 0, 0);
                    accB[0][st] = MFMAH(A00, b1, accB[0][st], 0, 0, 0);
                    accB[0][st] = MFMAH(A01, b0, accB[0][st], 0, 0, 0);
                    accA[1][st] = MFMAH(A10, b0, accA[1][st], 0, 0, 0);
                    accB[1][st] = MFMAH(A10, b1, accB[1][st], 0, 0, 0);
                    accB[1][st] = MFMAH(A11, b0, accB[1][st], 0, 0, 0);
                }
            }
        }
        __syncthreads();   // B2: all h1 reads done -> h2 overwrite safe

        // ---- h2 epilogue: combine, relu, pkrtz split, write planes ----
        {
            #pragma unroll
            for (int t = 0; t < 2; ++t) {
                #pragma unroll
                for (int st = 0; st < 2; ++st) {
                    float v[4];
                    #pragma unroll
                    for (int r = 0; r < 4; ++r)
                        v[r] = fmaxf(fmaf(INV2048, accB[t][st][r], accA[t][st][r]), 0.f);
                    half4 p0, p1;
                    split4_pk(v, p0, p1);
                    char* wp = plw + ewa[t][st];
                    *(half4*)(wp)        = p0;
                    *(half4*)(wp + 8192) = p1;
                }
            }
        }
        __syncthreads();   // B3: h2 planes ready

        // ---- GEMM3: waves 0..2, p-tile 16wv; cs unrolled ----
        f32x4 acc3A[2], acc3B[2];
        #pragma unroll
        for (int st = 0; st < 2; ++st) {
            acc3A[st] = (f32x4){0.f, 0.f, 0.f, 0.f};
            acc3B[st] = (f32x4){0.f, 0.f, 0.f, 0.f};
        }
        if (wv < 3) {
            const half8* W3F8 = (const half8*)W3F;
            int qb = (l * 3 + wv) * 4;
            #pragma unroll
            for (int cs = 0; cs < 4; ++cs) {
                half8 A0 = W3F8[((qb + cs) * 2 + 0) * 64 + ln];
                half8 A1 = W3F8[((qb + cs) * 2 + 1) * 64 + ln];
                #pragma unroll
                for (int st = 0; st < 2; ++st) {
                    half8 b0 = *(const half8*)(pl + rdaddr[st][cs]);
                    half8 b1 = *(const half8*)(pl + rdaddr[st][cs] + 8192);
                    acc3A[st] = MFMAH(A0, b0, acc3A[st], 0, 0, 0);
                    acc3B[st] = MFMAH(A0, b1, acc3B[st], 0, 0, 0);
                    acc3B[st] = MFMAH(A1, b0, acc3B[st], 0, 0, 0);
                }
            }
        }
        __syncthreads();   // B4: all h2 reads done -> pbuf overlay safe

        if (wv < 3) {
            #pragma unroll
            for (int st = 0; st < 2; ++st) {
                float4 pv;
                pv.x = fmaf(INV2048, acc3B[st][0], acc3A[st][0]);
                pv.y = fmaf(INV2048, acc3B[st][1], acc3A[st][1]);
                pv.z = fmaf(INV2048, acc3B[st][2], acc3A[st][2]);
                pv.w = fmaf(INV2048, acc3B[st][3], acc3A[st][3]);
                *(float4*)(plw + pwa[st]) = pv;   // pbuf[row][16wv+4qd .. +3]
            }
        }
        __syncthreads();   // B5: params visible

        // ---- spline: thread (f = tid>>5, s = tid&31); threads 0..63 ----
        if (tid < 64) {
            int f = tid >> 5, s = tid & 31;
            const float* b3l = b3 + l * 46;
            const float4* prow = (const float4*)(pl + s * 208);
            float pr[23];
            #pragma unroll
            for (int i = 0; i < 12; ++i) {
                float4 q = prow[i];                     // p = 4i .. 4i+3
                pr[2 * i] = (f ? q.y : q.x) + b3l[4 * i + f];
                if (2 * i + 1 < 23)
                    pr[2 * i + 1] = (f ? q.w : q.z) + b3l[4 * i + 2 + f];
            }

            float xin = xbuf[s][f == 0 ? ii0 : ii1];

            float d[9];
            d[0] = 1.f; d[8] = 1.f;
            #pragma unroll
            for (int k = 1; k < 8; ++k) d[k] = 1e-6f + softplus_f(pr[16 + k - 1]);

            bool inside = (xin >= -TAILB) && (xin <= TAILB);
            float xc = fminf(fmaxf(xin, -TAILB), TAILB);

            float mw = pr[0], mh = pr[8];
            #pragma unroll
            for (int k = 1; k < 8; ++k) { mw = fmaxf(mw, pr[k]); mh = fmaxf(mh, pr[8 + k]); }
            float ew[8], eh[8], swm = 0.f, shm = 0.f;
            #pragma unroll
            for (int k = 0; k < 8; ++k) {
                ew[k] = __expf(pr[k] - mw);     swm += ew[k];
                eh[k] = __expf(pr[8 + k] - mh); shm += eh[k];
            }
            const float c1 = 1.f - 8e-6f;
            float isw = __fdividef(c1, swm), ish = __fdividef(c1, shm);

            float cum_w = 0.f, cum_h = 0.f;
            float cwk = -TAILB, chk = -TAILB;
            float s_cw = -TAILB, s_w = 2.f * TAILB, s_ch = -TAILB, s_h = 2.f * TAILB;
            float s_d0 = 1.f, s_d1 = d[1];
            #pragma unroll
            for (int k = 0; k < 8; ++k) {
                cum_w += fmaf(ew[k], isw, 1e-6f);
                cum_h += fmaf(eh[k], ish, 1e-6f);
                float cwn = (k == 7) ? TAILB : fmaf(2.f * TAILB, cum_w, -TAILB);
                float chn = (k == 7) ? TAILB : fmaf(2.f * TAILB, cum_h, -TAILB);
                bool ge = (xc >= cwk);
                s_cw = ge ? cwk : s_cw;  s_w = ge ? (cwn - cwk) : s_w;
                s_ch = ge ? chk : s_ch;  s_h = ge ? (chn - chk) : s_h;
                s_d0 = ge ? d[k] : s_d0; s_d1 = ge ? d[k + 1] : s_d1;
                cwk = cwn; chk = chn;
            }

            float rw    = __fdividef(1.f, s_w);
            float th    = (xc - s_cw) * rw;
            float delta = s_h * rw;
            float omt   = 1.f - th;
            float tomt  = th * omt;
            float num   = s_h * fmaf(delta, th * th, s_d0 * tomt);
            float den   = fmaf(s_d0 + s_d1 - 2.f * delta, tomt, delta);
            float y     = s_ch + __fdividef(num, den);
            float dnum  = delta * delta * (s_d1 * th * th + 2.f * delta * tomt + s_d0 * omt * omt);
            float lad   = __logf(dnum) - 2.f * __logf(den);

            xbuf[s][f == 0 ? ii0 : ii1] = inside ? y : xin;
            ladreg += inside ? lad : 0.f;
        }
        __syncthreads();   // B6: spline done; next phase1 may overwrite planes
    } // l

    if (tid < 64) ladb[tid] = ladreg;
    __syncthreads();
    if (tid < 32) {
        float4 xo;
        xo.x = xbuf[tid][0]; xo.y = xbuf[tid][1];
        xo.z = xbuf[tid][2]; xo.w = xbuf[tid][3];
        reinterpret_cast<float4*>(out)[base + tid] = xo;
        out[(size_t)B * 4 + base + tid] = ladb[tid] + ladb[tid + 32];
    }
}

extern "C" void kernel_launch(void* const* d_in, const int* in_sizes, int n_in,
                              void* d_out, int out_size, void* d_ws, size_t ws_size,
                              hipStream_t stream) {
    const float* inp  = (const float*)d_in[0];
    const float* cond = (const float*)d_in[1];
    const float* W1   = (const float*)d_in[2];
    const float* b1   = (const float*)d_in[3];
    const float* W2   = (const float*)d_in[4];
    const float* b2   = (const float*)d_in[5];
    const float* W3   = (const float*)d_in[6];
    const float* b3   = (const float*)d_in[7];
    float* out = (float*)d_out;
    int B = in_sizes[0] / 4;

    char* ws = (char*)d_ws;
    _Float16* W2F = (_Float16*)(ws);            // 262144 B
    _Float16* W3F = (_Float16*)(ws + 262144);   // 98304 B
    float4*   w1p = (float4*)(ws + 360448);     // 8192 B

    hipLaunchKernelGGL(prep_v14, dim3(354), dim3(256), 0, stream,
                       W1, b1, W2, W3, W2F, W3F, w1p);
    hipLaunchKernelGGL(rqs_v14, dim3(B / 32), dim3(256), 0, stream,
                       inp, cond, W2F, W3F, w1p, b2, b3, out, B);
}